// Round 2
// 1891.333 us; speedup vs baseline: 2.1842x; 2.1842x over previous
//
#include <hip/hip_runtime.h>
#include <math.h>

#define LAYERS 2
#define B_ 2
#define S_ 1024
#define D_ 2048
#define F_ 5504
#define R_ 8
#define H_ 16
#define DH_ 128
#define M_ (B_*S_)   // 2048

typedef __attribute__((ext_vector_type(8))) short bf16x8;
typedef __attribute__((ext_vector_type(4))) short bf16x4;
typedef __attribute__((ext_vector_type(4))) float f32x4;

__device__ __forceinline__ float bf2f(unsigned short h) {
    unsigned u = ((unsigned)h) << 16;
    return __builtin_bit_cast(float, u);
}
__device__ __forceinline__ unsigned short f2bf(float f) {
    unsigned u = __builtin_bit_cast(unsigned, f);
    u += 0x7fffu + ((u >> 16) & 1u);
    return (unsigned short)(u >> 16);
}

// NF4: idx = searchsorted(mids, normed, left) == count(mids < normed)
__device__ __forceinline__ float nf4_deq(float v, float amax) {
    const float C0  = -1.0f;
    const float C1  = -0.6961928009986877f;
    const float C2  = -0.5250730514526367f;
    const float C3  = -0.39491748809814453f;
    const float C4  = -0.28444138169288635f;
    const float C5  = -0.18477343022823334f;
    const float C6  = -0.09105003625154495f;
    const float C7  = 0.0f;
    const float C8  = 0.07958029955625534f;
    const float C9  = 0.16093020141124725f;
    const float C10 = 0.24611230194568634f;
    const float C11 = 0.33791524171829224f;
    const float C12 = 0.44070982933044434f;
    const float C13 = 0.5626170039176941f;
    const float C14 = 0.7229568362236023f;
    const float C15 = 1.0f;
    float normed = v / fmaxf(amax, 1e-12f);
    float c = C0;
    c = (normed > 0.5f*(C0 +C1 )) ? C1  : c;
    c = (normed > 0.5f*(C1 +C2 )) ? C2  : c;
    c = (normed > 0.5f*(C2 +C3 )) ? C3  : c;
    c = (normed > 0.5f*(C3 +C4 )) ? C4  : c;
    c = (normed > 0.5f*(C4 +C5 )) ? C5  : c;
    c = (normed > 0.5f*(C5 +C6 )) ? C6  : c;
    c = (normed > 0.5f*(C6 +C7 )) ? C7  : c;
    c = (normed > 0.5f*(C7 +C8 )) ? C8  : c;
    c = (normed > 0.5f*(C8 +C9 )) ? C9  : c;
    c = (normed > 0.5f*(C9 +C10)) ? C10 : c;
    c = (normed > 0.5f*(C10+C11)) ? C11 : c;
    c = (normed > 0.5f*(C11+C12)) ? C12 : c;
    c = (normed > 0.5f*(C12+C13)) ? C13 : c;
    c = (normed > 0.5f*(C13+C14)) ? C14 : c;
    c = (normed > 0.5f*(C14+C15)) ? C15 : c;
    return c * amax;
}

__device__ __forceinline__ float silu_f(float x) { return x / (1.0f + expf(-x)); }

// ---------------------------------------------------------------------------
// Fused NF4 fake-quant: per-64-block absmax + dequant + bf16 cast.
// ---------------------------------------------------------------------------
__global__ __launch_bounds__(256) void dequant_bf16_kernel(
        const float* __restrict__ w, unsigned short* __restrict__ out, int nblk) {
    int b = blockIdx.x * 4 + (threadIdx.x >> 6);
    if (b >= nblk) return;
    int lane = threadIdx.x & 63;
    size_t idx = (size_t)b * 64 + lane;
    float v = w[idx];
    float m = fabsf(v);
    #pragma unroll
    for (int off = 32; off > 0; off >>= 1) m = fmaxf(m, __shfl_xor(m, off));
    out[idx] = f2bf(nf4_deq(v, m));
}

// ---------------------------------------------------------------------------
// RMSNorm: fp32 in, bf16 or fp32 out.
// ---------------------------------------------------------------------------
template<bool BF16OUT>
__global__ __launch_bounds__(256) void rmsnorm_kernel(const float* __restrict__ x,
                                                      const float* __restrict__ w,
                                                      void* __restrict__ out) {
    int row = blockIdx.x;
    const float* xr = x + (size_t)row * D_;
    float ss = 0.0f;
    for (int k = threadIdx.x; k < D_; k += 256) { float v = xr[k]; ss += v * v; }
    __shared__ float red[256];
    red[threadIdx.x] = ss; __syncthreads();
    for (int s = 128; s > 0; s >>= 1) {
        if (threadIdx.x < s) red[threadIdx.x] += red[threadIdx.x + s];
        __syncthreads();
    }
    float scale = 1.0f / sqrtf(red[0] / (float)D_ + 1e-5f);
    for (int k = threadIdx.x; k < D_; k += 256) {
        float v = xr[k] * scale * w[k];
        if (BF16OUT) ((unsigned short*)out)[(size_t)row * D_ + k] = f2bf(v);
        else         ((float*)out)[(size_t)row * D_ + k] = v;
    }
}

// ---------------------------------------------------------------------------
// LoRA A-projection: tA[m][r] = sum_k h[m,k] * A[r,k], h in bf16.
// ---------------------------------------------------------------------------
__global__ __launch_bounds__(256) void lora_a_kernel(const unsigned short* __restrict__ h,
                                                     const float* __restrict__ A,
                                                     float* __restrict__ tA) {
    int m = blockIdx.x;
    const unsigned short* hr = h + (size_t)m * D_;
    float acc[R_];
    #pragma unroll
    for (int r = 0; r < R_; ++r) acc[r] = 0.0f;
    for (int k = threadIdx.x; k < D_; k += 256) {
        float hv = bf2f(hr[k]);
        #pragma unroll
        for (int r = 0; r < R_; ++r) acc[r] += hv * A[(size_t)r * D_ + k];
    }
    __shared__ float red[256];
    for (int r = 0; r < R_; ++r) {
        red[threadIdx.x] = acc[r]; __syncthreads();
        for (int s = 128; s > 0; s >>= 1) {
            if (threadIdx.x < s) red[threadIdx.x] += red[threadIdx.x + s];
            __syncthreads();
        }
        if (threadIdx.x == 0) tA[(size_t)m * R_ + r] = red[0];
        __syncthreads();
    }
}

// ---------------------------------------------------------------------------
// MFMA bf16 GEMM, m97 structure: 128x128 tile, BK=32, 4 waves (2x2 of 64x64),
// each wave 4x4 grid of 16x16x32 MFMA. global_load_lds width=16 staging.
// ---------------------------------------------------------------------------
struct GemmPtrs {
    const unsigned short* W[3];
    const float* tA[3];
    const float* lB[3];
    void* Y[3];
};

__device__ __forceinline__ void load_lds16(const void* g, void* l) {
    __builtin_amdgcn_global_load_lds(
        (__attribute__((address_space(1))) void*)g,
        (__attribute__((address_space(3))) void*)l, 16, 0, 0);
}

template<int ACT, bool HAS_LORA, bool HAS_RESID, bool OUT_BF16>
__global__ __launch_bounds__(256) void gemm_mfma_kernel(
        const unsigned short* __restrict__ X, GemmPtrs P,
        const float* __restrict__ resid,
        int Kdim, int Ndim, int nbper) {
    __shared__ __align__(16) unsigned short As[128 * 32];
    __shared__ __align__(16) unsigned short Bs[128 * 32];

    const int tid  = threadIdx.x;
    const int lane = tid & 63;
    const int wave = tid >> 6;
    int bn = blockIdx.x;
    const int bm = blockIdx.y;
    const int sel = bn / nbper;
    bn -= sel * nbper;

    const unsigned short* W = P.W[sel];

    const int wm = (wave & 1) * 64;
    const int wn = (wave >> 1) * 64;

    f32x4 acc[4][4] = {};

    const int lrow = lane >> 2;        // 0..15
    const int lcol = (lane & 3) * 8;   // 0,8,16,24 (shorts)
    const unsigned short* Ag = X + (size_t)(bm * 128) * Kdim;
    const unsigned short* Wg = W + (size_t)(bn * 128) * Kdim;
    const unsigned short* a0 = Ag + (size_t)(wave * 16 + lrow) * Kdim + lcol;
    const unsigned short* a1 = Ag + (size_t)(64 + wave * 16 + lrow) * Kdim + lcol;
    const unsigned short* b0 = Wg + (size_t)(wave * 16 + lrow) * Kdim + lcol;
    const unsigned short* b1 = Wg + (size_t)(64 + wave * 16 + lrow) * Kdim + lcol;
    unsigned short* lA0 = &As[(wave * 16) * 32];
    unsigned short* lA1 = &As[(64 + wave * 16) * 32];
    unsigned short* lB0 = &Bs[(wave * 16) * 32];
    unsigned short* lB1 = &Bs[(64 + wave * 16) * 32];

    const int fr = lane & 15;
    const int fk = (lane >> 4) * 8;

    for (int kt = 0; kt < Kdim; kt += 32) {
        __syncthreads();
        load_lds16(a0 + kt, lA0);
        load_lds16(a1 + kt, lA1);
        load_lds16(b0 + kt, lB0);
        load_lds16(b1 + kt, lB1);
        __syncthreads();
        bf16x8 af[4], bf[4];
        #pragma unroll
        for (int i = 0; i < 4; ++i)
            af[i] = *(const bf16x8*)&As[(wm + i * 16 + fr) * 32 + fk];
        #pragma unroll
        for (int j = 0; j < 4; ++j)
            bf[j] = *(const bf16x8*)&Bs[(wn + j * 16 + fr) * 32 + fk];
        #pragma unroll
        for (int i = 0; i < 4; ++i)
            #pragma unroll
            for (int j = 0; j < 4; ++j)
                acc[i][j] = __builtin_amdgcn_mfma_f32_16x16x32_bf16(
                    af[i], bf[j], acc[i][j], 0, 0, 0);
    }

    // Epilogue. C/D layout: col = lane&15, row = (lane>>4)*4 + reg.
    const int colq = bn * 128 + wn + fr;
    const int rowq = bm * 128 + wm + (lane >> 4) * 4;

    float lbv[4][R_];
    if (HAS_LORA) {
        const float* lB = P.lB[sel];
        #pragma unroll
        for (int j = 0; j < 4; ++j)
            #pragma unroll
            for (int rr = 0; rr < R_; ++rr)
                lbv[j][rr] = lB[(size_t)(colq + j * 16) * R_ + rr];
    }

    #pragma unroll
    for (int i = 0; i < 4; ++i) {
        #pragma unroll
        for (int r = 0; r < 4; ++r) {
            const int row = rowq + i * 16 + r;
            float lam[R_];
            if (HAS_LORA) {
                const float* tA = P.tA[sel];
                #pragma unroll
                for (int rr = 0; rr < R_; ++rr) lam[rr] = tA[(size_t)row * R_ + rr];
            }
            #pragma unroll
            for (int j = 0; j < 4; ++j) {
                float v = acc[i][j][r];
                if (HAS_LORA) {
                    #pragma unroll
                    for (int rr = 0; rr < R_; ++rr) v += 2.0f * lam[rr] * lbv[j][rr];
                }
                if (ACT == 1) v = silu_f(v);
                const int col = colq + j * 16;
                size_t off = (size_t)row * Ndim + col;
                if (HAS_RESID) v += resid[off];
                if (OUT_BF16) ((unsigned short*)P.Y[sel])[off] = f2bf(v);
                else          ((float*)P.Y[sel])[off] = v;
            }
        }
    }
}

// ---------------------------------------------------------------------------
// RoPE in place on q,k (fp32). Grid (S, H, 2*B), 128 threads.
// ---------------------------------------------------------------------------
__global__ __launch_bounds__(128) void rope_kernel(float* __restrict__ q, float* __restrict__ k) {
    int s = blockIdx.x, h = blockIdx.y, bz = blockIdx.z;
    float* buf = (bz < B_) ? q : k;
    int b = bz & 1;
    int d = threadIdx.x;
    size_t base = (((size_t)b * S_ + s) * H_ + h) * DH_;
    int j = d & 63;
    float inv_freq = powf(10000.0f, -((float)j) / 64.0f);
    float ang = (float)s * inv_freq;
    float cv = cosf(ang), sv = sinf(ang);
    float x = buf[base + d];
    float other = (d < 64) ? -buf[base + d + 64] : buf[base + d - 64];
    __syncthreads();
    buf[base + d] = x * cv + other * sv;
}

// ---------------------------------------------------------------------------
// Flash-style MFMA attention.
// Grid (S/64, H, B), 256 threads = 4 waves; wave w owns q-rows [qt*64+w*16, +16).
// Per 64-key tile: stage K row-major (pad 136) + V transposed (stride 68) as
// bf16 in LDS; QK^T via 16 MFMAs; online softmax in fp32 (rows in 16-lane
// groups -> shfl_xor reduce); P acc->A-frag via per-wave LDS buffer; PV via
// 16 MFMAs. Causal balance: qt = b ? 15-qt : qt.
// Pad strides chosen so full-wave b128/b64 reads hit the LDS bank floor:
//   KSTR=136 (b128: 8 dwords/bank = floor), VSTR=68 (b64: 4/bank = floor),
//   PSTR=72  (b128: 8/bank = floor).
// ---------------------------------------------------------------------------
__global__ __launch_bounds__(256, 2) void attn_kernel(const float* __restrict__ q,
                                                      const float* __restrict__ k,
                                                      const float* __restrict__ v,
                                                      const int* __restrict__ mask,
                                                      unsigned short* __restrict__ ctx) {
    const int KSTR = 136;   // K row stride (shorts)
    const int VSTR = 68;    // Vt row stride (shorts): 64 keys + 4 pad
    const int PSTR = 72;    // P row stride (shorts)
    __shared__ unsigned short Ks[64 * 136];
    __shared__ unsigned short Vt[128 * 68];
    __shared__ unsigned short Ps[4][16 * 72];
    __shared__ int smask[64];

    const int tid  = threadIdx.x;
    const int lane = tid & 63;
    const int wave = tid >> 6;
    const int h = blockIdx.y, b = blockIdx.z;
    int qt = blockIdx.x;
    if (b) qt = gridDim.x - 1 - qt;          // pair (qt, 15-qt) per CU
    const int qr0 = qt * 64 + wave * 16;
    const int fr = lane & 15;
    const int fk = (lane >> 4) * 8;
    const int rbase = (lane >> 4) * 4;

    // Q fragments, pre-scaled by 1/sqrt(Dh). A-frag: row = lane&15, k = fk+0..7.
    const float inv = 0.08838834764831845f;
    bf16x8 qa[4];
    {
        const float* qp = q + (((size_t)b * S_ + (qr0 + fr)) * H_ + h) * DH_ + fk;
        #pragma unroll
        for (int c = 0; c < 4; ++c) {
            f32x4 u0 = *(const f32x4*)(qp + c * 32);
            f32x4 u1 = *(const f32x4*)(qp + c * 32 + 4);
            bf16x8 r;
            r[0] = f2bf(u0[0] * inv); r[1] = f2bf(u0[1] * inv);
            r[2] = f2bf(u0[2] * inv); r[3] = f2bf(u0[3] * inv);
            r[4] = f2bf(u1[0] * inv); r[5] = f2bf(u1[1] * inv);
            r[6] = f2bf(u1[2] * inv); r[7] = f2bf(u1[3] * inv);
            qa[c] = r;
        }
    }

    float m_run[4], l_run[4];
    f32x4 oacc[8];
    #pragma unroll
    for (int r = 0; r < 4; ++r) { m_run[r] = -1e30f; l_run[r] = 0.0f; }
    #pragma unroll
    for (int ot = 0; ot < 8; ++ot) oacc[ot] = (f32x4){0.f, 0.f, 0.f, 0.f};

    for (int it = 0; it <= qt; ++it) {
        const int k0 = it * 64;
        __syncthreads();
        // ---- stage K tile [64][128] fp32 -> bf16 row-major (padded) ----
        {
            const int jr = tid >> 5;          // 0..7
            const int jc = (tid & 31) * 4;    // 0..124
            #pragma unroll
            for (int m = 0; m < 8; ++m) {
                int rr = jr + m * 8;
                const float* src = k + (((size_t)b * S_ + (k0 + rr)) * H_ + h) * DH_ + jc;
                f32x4 u = *(const f32x4*)src;
                bf16x4 w4;
                w4[0] = f2bf(u[0]); w4[1] = f2bf(u[1]);
                w4[2] = f2bf(u[2]); w4[3] = f2bf(u[3]);
                *(bf16x4*)&Ks[rr * KSTR + jc] = w4;
            }
        }
        // ---- stage V tile transposed: Vt[d][kp] bf16 ----
        {
            const int c  = tid & 127;          // column d
            const int rh = (tid >> 7) * 4;     // 0 or 4
            #pragma unroll
            for (int m = 0; m < 8; ++m) {
                int r0 = rh + m * 8;
                const float* vs = v + (((size_t)b * S_ + (k0 + r0)) * H_ + h) * DH_ + c;
                bf16x4 w4;
                w4[0] = f2bf(vs[0]);
                w4[1] = f2bf(vs[H_ * DH_]);
                w4[2] = f2bf(vs[2 * H_ * DH_]);
                w4[3] = f2bf(vs[3 * H_ * DH_]);
                *(bf16x4*)&Vt[c * VSTR + r0] = w4;
            }
        }
        if (tid < 64) smask[tid] = mask[(size_t)b * S_ + k0 + tid];
        __syncthreads();

        // ---- QK^T: D[row=q (lane>>4)*4+reg, col=key lane&15] ----
        f32x4 sacc[4];
        #pragma unroll
        for (int ct = 0; ct < 4; ++ct) sacc[ct] = (f32x4){0.f, 0.f, 0.f, 0.f};
        #pragma unroll
        for (int c = 0; c < 4; ++c) {
            #pragma unroll
            for (int ct = 0; ct < 4; ++ct) {
                bf16x8 kf = *(const bf16x8*)&Ks[(ct * 16 + fr) * KSTR + c * 32 + fk];
                sacc[ct] = __builtin_amdgcn_mfma_f32_16x16x32_bf16(qa[c], kf, sacc[ct], 0, 0, 0);
            }
        }

        // ---- online softmax (fp32), rows in 16-lane groups ----
        float sc[4][4];
        #pragma unroll
        for (int r = 0; r < 4; ++r) {
            const int qrow = qr0 + rbase + r;
            float mx = -1e30f;
            #pragma unroll
            for (int ct = 0; ct < 4; ++ct) {
                int kp = k0 + ct * 16 + fr;
                float s = sacc[ct][r];
                s = (kp <= qrow && smask[ct * 16 + fr]) ? s : -1e9f;
                sc[r][ct] = s;
                mx = fmaxf(mx, s);
            }
            mx = fmaxf(mx, __shfl_xor(mx, 1));
            mx = fmaxf(mx, __shfl_xor(mx, 2));
            mx = fmaxf(mx, __shfl_xor(mx, 4));
            mx = fmaxf(mx, __shfl_xor(mx, 8));
            float mnew = fmaxf(m_run[r], mx);
            float corr = __expf(m_run[r] - mnew);
            m_run[r] = mnew;
            float rs = 0.0f;
            #pragma unroll
            for (int ct = 0; ct < 4; ++ct) {
                float p = __expf(sc[r][ct] - mnew);
                sc[r][ct] = p;
                rs += p;
            }
            rs += __shfl_xor(rs, 1);
            rs += __shfl_xor(rs, 2);
            rs += __shfl_xor(rs, 4);
            rs += __shfl_xor(rs, 8);
            l_run[r] = l_run[r] * corr + rs;
            #pragma unroll
            for (int ot = 0; ot < 8; ++ot) oacc[ot][r] *= corr;
        }

        // ---- P: acc layout -> A-frag layout via per-wave LDS ----
        unsigned short* Pw = Ps[wave];
        #pragma unroll
        for (int r = 0; r < 4; ++r)
            #pragma unroll
            for (int ct = 0; ct < 4; ++ct)
                Pw[(rbase + r) * PSTR + ct * 16 + fr] = f2bf(sc[r][ct]);
        asm volatile("s_waitcnt lgkmcnt(0)" ::: "memory");
        __builtin_amdgcn_sched_barrier(0);

        // ---- PV: O[q][d] += P[q][k] * V[k][d], B-frag from Vt[d][k] ----
        #pragma unroll
        for (int kc = 0; kc < 2; ++kc) {
            bf16x8 pf = *(const bf16x8*)&Pw[fr * PSTR + kc * 32 + fk];
            #pragma unroll
            for (int ot = 0; ot < 8; ++ot) {
                bf16x4 v0 = *(const bf16x4*)&Vt[(ot * 16 + fr) * VSTR + kc * 32 + fk];
                bf16x4 v1 = *(const bf16x4*)&Vt[(ot * 16 + fr) * VSTR + kc * 32 + fk + 4];
                bf16x8 vf;
                vf[0] = v0[0]; vf[1] = v0[1]; vf[2] = v0[2]; vf[3] = v0[3];
                vf[4] = v1[0]; vf[5] = v1[1]; vf[6] = v1[2]; vf[7] = v1[3];
                oacc[ot] = __builtin_amdgcn_mfma_f32_16x16x32_bf16(pf, vf, oacc[ot], 0, 0, 0);
            }
        }
    }

    // ---- epilogue: normalize and store bf16 ctx ----
    #pragma unroll
    for (int r = 0; r < 4; ++r) {
        const int qrow = qr0 + rbase + r;
        const float pinv = 1.0f / l_run[r];
        unsigned short* cp = ctx + (((size_t)b * S_ + qrow) * H_ + h) * DH_;
        #pragma unroll
        for (int ot = 0; ot < 8; ++ot)
            cp[ot * 16 + fr] = f2bf(oacc[ot][r] * pinv);
    }
}

// ---------------------------------------------------------------------------
// In-place: gate[i] = bf16(gate[i] * up[i])   (silu already applied in GEMM)
// ---------------------------------------------------------------------------
__global__ void mul_kernel(unsigned short* __restrict__ a,
                           const unsigned short* __restrict__ b, size_t n) {
    size_t i = (size_t)blockIdx.x * 256 + threadIdx.x;
    if (i < n) a[i] = f2bf(bf2f(a[i]) * bf2f(b[i]));
}

extern "C" void kernel_launch(void* const* d_in, const int* in_sizes, int n_in,
                              void* d_out, int out_size, void* d_ws, size_t ws_size,
                              hipStream_t stream) {
    const float* embeds = (const float*)d_in[0];
    const int*   amask  = (const int*)d_in[1];
    const float* wq = (const float*)d_in[2];
    const float* aq = (const float*)d_in[3];
    const float* bq = (const float*)d_in[4];
    const float* wk = (const float*)d_in[5];
    const float* ak = (const float*)d_in[6];
    const float* bk = (const float*)d_in[7];
    const float* wv = (const float*)d_in[8];
    const float* av = (const float*)d_in[9];
    const float* bv = (const float*)d_in[10];
    const float* wo = (const float*)d_in[11];
    const float* ao = (const float*)d_in[12];
    const float* bo = (const float*)d_in[13];
    const float* ln1 = (const float*)d_in[14];
    const float* wg = (const float*)d_in[15];
    const float* wu = (const float*)d_in[16];
    const float* wd = (const float*)d_in[17];
    const float* ln2 = (const float*)d_in[18];
    const float* normf = (const float*)d_in[19];
    float* outp = (float*)d_out;

    const size_t DD = (size_t)D_ * D_;     // 4.19M
    const size_t FD = (size_t)F_ * D_;     // 11.27M

    char* p = (char*)d_ws;
    unsigned short* wbuf = (unsigned short*)p; p += 3 * DD * sizeof(unsigned short);
    float* x    = (float*)p;          p += (size_t)M_ * D_ * sizeof(float);
    unsigned short* h = (unsigned short*)p; p += (size_t)M_ * D_ * sizeof(unsigned short);
    float* qb   = (float*)p;          p += (size_t)M_ * D_ * sizeof(float);
    float* kb   = (float*)p;          p += (size_t)M_ * D_ * sizeof(float);
    float* vbuf = (float*)p;          p += (size_t)M_ * D_ * sizeof(float);
    unsigned short* ctx = (unsigned short*)p; p += (size_t)M_ * D_ * sizeof(unsigned short);
    unsigned short* gate = (unsigned short*)p; p += (size_t)M_ * F_ * sizeof(unsigned short);
    unsigned short* up   = (unsigned short*)p; p += (size_t)M_ * F_ * sizeof(unsigned short);
    float* tA0 = (float*)p; p += (size_t)M_ * R_ * sizeof(float);
    float* tA1 = (float*)p; p += (size_t)M_ * R_ * sizeof(float);
    float* tA2 = (float*)p; p += (size_t)M_ * R_ * sizeof(float);

    hipMemcpyAsync(x, embeds, (size_t)M_ * D_ * sizeof(float),
                   hipMemcpyDeviceToDevice, stream);

    const int DDblk = (int)(DD / 64);   // 65536
    const int FDblk = (int)(FD / 64);   // 176128

    for (int l = 0; l < LAYERS; ++l) {
        const float* wq_l = wq + l * DD;
        const float* wk_l = wk + l * DD;
        const float* wv_l = wv + l * DD;
        const float* wo_l = wo + l * DD;
        const float* aq_l = aq + (size_t)l * R_ * D_;
        const float* ak_l = ak + (size_t)l * R_ * D_;
        const float* av_l = av + (size_t)l * R_ * D_;
        const float* ao_l = ao + (size_t)l * R_ * D_;
        const float* bq_l = bq + (size_t)l * D_ * R_;
        const float* bk_l = bk + (size_t)l * D_ * R_;
        const float* bv_l = bv + (size_t)l * D_ * R_;
        const float* bo_l = bo + (size_t)l * D_ * R_;
        const float* ln1_l = ln1 + (size_t)l * D_;
        const float* ln2_l = ln2 + (size_t)l * D_;
        const float* wg_l = wg + l * FD;
        const float* wu_l = wu + l * FD;
        const float* wd_l = wd + l * FD;

        // ---- attention block ----
        rmsnorm_kernel<true><<<M_, 256, 0, stream>>>(x, ln1_l, h);

        dequant_bf16_kernel<<<(DDblk + 3) / 4, 256, 0, stream>>>(wq_l, wbuf, DDblk);
        dequant_bf16_kernel<<<(DDblk + 3) / 4, 256, 0, stream>>>(wk_l, wbuf + DD, DDblk);
        dequant_bf16_kernel<<<(DDblk + 3) / 4, 256, 0, stream>>>(wv_l, wbuf + 2 * DD, DDblk);

        lora_a_kernel<<<M_, 256, 0, stream>>>(h, aq_l, tA0);
        lora_a_kernel<<<M_, 256, 0, stream>>>(h, ak_l, tA1);
        lora_a_kernel<<<M_, 256, 0, stream>>>(h, av_l, tA2);

        {
            GemmPtrs P;
            P.W[0] = wbuf; P.W[1] = wbuf + DD; P.W[2] = wbuf + 2 * DD;
            P.tA[0] = tA0; P.tA[1] = tA1; P.tA[2] = tA2;
            P.lB[0] = bq_l; P.lB[1] = bk_l; P.lB[2] = bv_l;
            P.Y[0] = qb; P.Y[1] = kb; P.Y[2] = vbuf;
            gemm_mfma_kernel<0, true, false, false><<<dim3(48, 16), 256, 0, stream>>>(
                h, P, nullptr, D_, D_, 16);
        }

        rope_kernel<<<dim3(S_, H_, 2 * B_), 128, 0, stream>>>(qb, kb);
        attn_kernel<<<dim3(S_ / 64, H_, B_), 256, 0, stream>>>(qb, kb, vbuf, amask, ctx);

        // o-projection + residual into x
        dequant_bf16_kernel<<<(DDblk + 3) / 4, 256, 0, stream>>>(wo_l, wbuf, DDblk);
        lora_a_kernel<<<M_, 256, 0, stream>>>(ctx, ao_l, tA0);
        {
            GemmPtrs P = {};
            P.W[0] = wbuf; P.tA[0] = tA0; P.lB[0] = bo_l; P.Y[0] = x;
            gemm_mfma_kernel<0, true, true, false><<<dim3(16, 16), 256, 0, stream>>>(
                ctx, P, x, D_, D_, 16);
        }

        // ---- MLP block ----
        rmsnorm_kernel<true><<<M_, 256, 0, stream>>>(x, ln2_l, h);

        dequant_bf16_kernel<<<(FDblk + 3) / 4, 256, 0, stream>>>(wg_l, wbuf, FDblk);
        {
            GemmPtrs P = {};
            P.W[0] = wbuf; P.Y[0] = gate;
            gemm_mfma_kernel<1, false, false, true><<<dim3(43, 16), 256, 0, stream>>>(
                h, P, nullptr, D_, F_, 43);
        }
        dequant_bf16_kernel<<<(FDblk + 3) / 4, 256, 0, stream>>>(wu_l, wbuf, FDblk);
        {
            GemmPtrs P = {};
            P.W[0] = wbuf; P.Y[0] = up;
            gemm_mfma_kernel<0, false, false, true><<<dim3(43, 16), 256, 0, stream>>>(
                h, P, nullptr, D_, F_, 43);
        }
        mul_kernel<<<(int)(((size_t)M_ * F_ + 255) / 256), 256, 0, stream>>>(
            gate, up, (size_t)M_ * F_);

        dequant_bf16_kernel<<<(FDblk + 3) / 4, 256, 0, stream>>>(wd_l, wbuf, FDblk);
        {
            GemmPtrs P = {};
            P.W[0] = wbuf; P.Y[0] = x;
            gemm_mfma_kernel<0, false, true, false><<<dim3(16, 16), 256, 0, stream>>>(
                gate, P, x, F_, D_, 16);
        }
    }

    rmsnorm_kernel<false><<<M_, 256, 0, stream>>>(x, normf, outp);
}